// Round 5
// baseline (291.060 us; speedup 1.0000x reference)
//
#include <hip/hip_runtime.h>
#include <math.h>

// SSIM loss, (32,3,512,512) fp32, 11x11 sigma=1.5 separable Gaussian, VALID.
// R10 = R9 with the second dispatch fused away via a fence-free coherent
// reduction protocol (compute phases byte-identical to R9).
// Bench arithmetic across R5-R9: each kernel node costs ~57 us of harness
// overhead (memset node ~2 us). The reduce kernel's dispatch is now the
// largest single cost. R6's fusion failed because __threadfence() lowers to
// buffer_wbl2+vmcnt(0) (L2 writeback) per block x 12288 = 490 us; R8 showed
// 12288 same-address RMWs cost ~60 us. R10 avoids both:
//  - partial[] written with RELAXED AGENT atomic store (sc0 sc1 write-through
//    -> never dirty in local L2, no wbl2 needed), then explicit
//    s_waitcnt vmcnt(0), then RELAXED AGENT fetch_add on a PER-PLANE counter
//    (96 counters x 128 increments: no global serialization).
//  - plane-last block reduces its 128 partials via AGENT atomic loads
//    (bypass stale local L2; d_ws is reused across graph replays), publishes
//    plane sum the same way, bumps a 96-wide global counter; 96th arrival
//    reduces plane sums in double and writes out.
//  - memset(512 B) resets only the counters.
// Inherited from R9/R8/R7:
//  - 4 conv fields {x, y, (x+y)^2, (x-y)^2}: sig1+sig2 = (P+M)/2 - mu1^2-mu2^2,
//    sig12 = (P-M)/4 - mu1*mu2.  LDS 39424 B -> 4 blocks/CU.
//  - phase-1 round 1: 4 full waves, SGPR row base, clamp-free interior path;
//    round 2: wave 0 does the 4x10 tail cols.
//  - phase-2: stride-77 scalar b32 LDS reads (2-way max = free), 8 outputs/
//    thread, relu folded into SSIM numerator, one rcp.

#define WIN   11
#define IMG   512
#define OUT_N 502
#define TO_R  32                 // output rows per block
#define TO_C  64                 // output cols per block
#define TI_C  (TO_C + WIN - 1)   // 74 input cols
#define VB_W  77                 // ODD row stride -> conflict-free scalar reads
#define NF    4                  // conv fields: x, y, (x+y)^2, (x-y)^2
#define C1F   6.5025f
#define C2F   58.5225f
#define GRID_X 8
#define GRID_Y 16
#define GRID_Z 96
#define BLKS_PER_PLANE (GRID_X * GRID_Y)     // 128

struct GaussW { float w[WIN]; };

// Vertical 11-tap over 18 input rows -> 8 output rows x 4 fields, one column.
// CR: clamp rows (only last row-block). CC: clamp column (round-2 tail only).
template<bool CR, bool CC>
__device__ __forceinline__ void vert_task(
    const float* __restrict__ Xp, const float* __restrict__ Yp,
    const GaussW& gw, float (*vb)[TO_R][VB_W],
    int r0, int gc, int i0, int c)
{
    if (CC) gc = min(gc, IMG - 1);
    float a0[8] = {0}, a1[8] = {0}, a2[8] = {0}, a3[8] = {0};
#pragma unroll
    for (int k = 0; k < 18; ++k) {            // 8 outputs need 18 input rows
        int gr = r0 + k;
        if (CR) gr = min(gr, IMG - 1);
        size_t off = (size_t)gr * IMG + gc;   // uniform part scalarizes when
        float x = Xp[off];                    // r0 came from readfirstlane
        float y = Yp[off];
        float s = x + y, d = x - y;
        float ss = s * s, dd = d * d;
        const int jlo = (k > 10) ? (k - 10) : 0;
        const int jhi = (k < 7) ? k : 7;
#pragma unroll
        for (int j = jlo; j <= jhi; ++j) {
            float wv = gw.w[k - j];
            a0[j] += wv * x;
            a1[j] += wv * y;
            a2[j] += wv * ss;
            a3[j] += wv * dd;
        }
    }
#pragma unroll
    for (int j = 0; j < 8; ++j) {             // stride-1 across lanes: free
        int i = i0 + j;
        vb[0][i][c] = a0[j];
        vb[1][i][c] = a1[j];
        vb[2][i][c] = a2[j];
        vb[3][i][c] = a3[j];
    }
}

// ws layout (bytes):
//   [0   .. 383]  96 u32 plane counters   (memset to 0 each iteration)
//   [384 .. 387]  1  u32 global counter   (memset covers first 512 B)
//   [512 .. 895]  96 f32 plane sums       (overwritten before read)
//   [1024 .. ]    12288 f32 block partials (overwritten before read)
__global__ __launch_bounds__(256) void ssim_v10_kernel(
    const float* __restrict__ X, const float* __restrict__ Y,
    GaussW gw, unsigned int* __restrict__ ws_u32, float* __restrict__ out)
{
    unsigned int* pctr     = ws_u32;                    // [96]
    unsigned int* gctr     = ws_u32 + 96;               // [1] at byte 384
    float*        planesum = (float*)(ws_u32 + 128);    // byte 512
    float*        partial  = (float*)(ws_u32 + 256);    // byte 1024

    // vertically filtered fields: [field][out_row][col], stride 77
    __shared__ float vb[NF][TO_R][VB_W];  // 39424 B -> 4 blocks/CU

    const int plane = blockIdx.z;
    const int ox0 = blockIdx.x * TO_C;    // 64-aligned global columns
    const int oy0 = blockIdx.y * TO_R;
    const float* Xp = X + (size_t)plane * IMG * IMG;
    const float* Yp = Y + (size_t)plane * IMG * IMG;
    const int tid  = threadIdx.x;
    const int wave = tid >> 6;
    const int lane = tid & 63;

    // ---- Phase 1: vertical 11-tap ----
    // Round 1: strip = wave, col = lane. Rows wave-uniform -> SGPR base.
    // gc = ox0 + lane <= 448 + 63 = 511: never needs the col clamp.
    {
        const int r0 = __builtin_amdgcn_readfirstlane(oy0 + wave * 8);
        const int gc = ox0 + lane;
        if (blockIdx.y == GRID_Y - 1)
            vert_task<true,  false>(Xp, Yp, gw, vb, r0, gc, wave * 8, lane);
        else
            vert_task<false, false>(Xp, Yp, gw, vb, r0, gc, wave * 8, lane);
    }
    // Round 2: wave 0 covers the 4 strips x 10 tail cols (c = 64..73).
    // Always fully clamped (40 lanes; clamps are no-ops on interior blocks).
    if (wave == 0 && lane < 40) {
        const int s = lane / 10;              // compiler magic-muls
        const int c = TO_C + (lane - s * 10); // 64..73
        vert_task<true, true>(Xp, Yp, gw, vb, oy0 + s * 8, ox0 + c, s * 8, c);
    }
    __syncthreads();

    // ---- Phase 2: horizontal 11-tap + SSIM, 8 outputs/thread ----
    const int i  = tid >> 3;              // 0..31
    const int c0 = (tid & 7) * 8;         // 0..56
    const int gi = oy0 + i;
    float m[NF][8];
#pragma unroll
    for (int f = 0; f < NF; ++f) {
        float v[18];
#pragma unroll
        for (int k = 0; k < 18; ++k) v[k] = vb[f][i][c0 + k];  // b32, 2-way max
#pragma unroll
        for (int oc = 0; oc < 8; ++oc) {
            float s = 0.f;
#pragma unroll
            for (int k = 0; k < WIN; ++k) s += gw.w[k] * v[oc + k];
            m[f][oc] = s;
        }
    }

    float psum = 0.f;
#pragma unroll
    for (int oc = 0; oc < 8; ++oc) {
        int gj = ox0 + c0 + oc;
        if (gi < OUT_N && gj < OUT_N) {
            float m1 = m[0][oc], m2 = m[1][oc];
            float P  = m[2][oc], M  = m[3][oc];
            float mu1s = m1 * m1, mu2s = m2 * m2, mu12 = m1 * m2;
            float sumvar = 0.5f  * (P + M) - mu1s - mu2s;   // sig1+sig2
            float sig12  = 0.25f * (P - M) - mu12;
            // ssim = [(2mu12+C1)/(mu1s+mu2s+C1)] * relu[(2sig12+C2)/(sumvar+C2)]
            // first factor and both denominators are > 0 -> relu folds into num.
            float num = (2.f * mu12 + C1F) * (2.f * sig12 + C2F);
            float den = (mu1s + mu2s + C1F) * (sumvar + C2F);
            num = fmaxf(num, 0.f);
            psum += num * __builtin_amdgcn_rcpf(den);
        }
    }

    // ---- block reduction ----
#pragma unroll
    for (int off = 32; off > 0; off >>= 1)
        psum += __shfl_down(psum, off, 64);
    __shared__ float wsum[4];
    if ((tid & 63) == 0) wsum[tid >> 6] = psum;
    __syncthreads();

    // ---- fence-free cross-block reduction protocol ----
    __shared__ int role;
    if (tid == 0) {
        float s = wsum[0] + wsum[1] + wsum[2] + wsum[3];
        const int pidx = plane * BLKS_PER_PLANE + blockIdx.y * GRID_X + blockIdx.x;
        // coherent (sc0 sc1) store: write-through, never dirty in local L2
        __hip_atomic_store(&partial[pidx], s, __ATOMIC_RELAXED,
                           __HIP_MEMORY_SCOPE_AGENT);
        // order: partial store reaches coherence point before counter bump
        asm volatile("s_waitcnt vmcnt(0)" ::: "memory");
        unsigned old = __hip_atomic_fetch_add(&pctr[plane], 1u,
                           __ATOMIC_RELAXED, __HIP_MEMORY_SCOPE_AGENT);
        role = (old == BLKS_PER_PLANE - 1) ? 1 : 0;
    }
    __syncthreads();

    if (role) {
        // plane-last block: reduce this plane's 128 partials
        float v = 0.f;
        if (tid < BLKS_PER_PLANE)
            v = __hip_atomic_load(&partial[plane * BLKS_PER_PLANE + tid],
                                  __ATOMIC_RELAXED, __HIP_MEMORY_SCOPE_AGENT);
#pragma unroll
        for (int off = 32; off > 0; off >>= 1)
            v += __shfl_down(v, off, 64);
        if ((tid & 63) == 0) wsum[tid >> 6] = v;
        __syncthreads();
        if (tid == 0) {
            float ps = wsum[0] + wsum[1] + wsum[2] + wsum[3];
            __hip_atomic_store(&planesum[plane], ps, __ATOMIC_RELAXED,
                               __HIP_MEMORY_SCOPE_AGENT);
            asm volatile("s_waitcnt vmcnt(0)" ::: "memory");
            unsigned o2 = __hip_atomic_fetch_add(gctr, 1u,
                               __ATOMIC_RELAXED, __HIP_MEMORY_SCOPE_AGENT);
            role = (o2 == GRID_Z - 1) ? 2 : 0;
        }
        __syncthreads();
        if (role == 2) {
            // globally-last block: reduce 96 plane sums in double, finalize
            double v2 = 0.0;
            if (tid < GRID_Z)
                v2 = (double)__hip_atomic_load(&planesum[tid],
                               __ATOMIC_RELAXED, __HIP_MEMORY_SCOPE_AGENT);
#pragma unroll
            for (int off = 32; off > 0; off >>= 1)
                v2 += __shfl_down(v2, off, 64);
            __shared__ double dsum[4];
            if ((tid & 63) == 0) dsum[tid >> 6] = v2;
            __syncthreads();
            if (tid == 0) {
                double a = dsum[0] + dsum[1] + dsum[2] + dsum[3];
                const double count = (double)GRID_Z * OUT_N * OUT_N;
                out[0] = (float)(1.0 - a / count);
            }
        }
    }
}

extern "C" void kernel_launch(void* const* d_in, const int* in_sizes, int n_in,
                              void* d_out, int out_size, void* d_ws, size_t ws_size,
                              hipStream_t stream) {
    (void)in_sizes; (void)n_in; (void)out_size; (void)ws_size;
    const float* X = (const float*)d_in[0];
    const float* Y = (const float*)d_in[1];
    float* out = (float*)d_out;
    unsigned int* ws_u32 = (unsigned int*)d_ws;

    // reset counters only (first 512 B); partials/plane sums are
    // overwritten before being read.
    hipMemsetAsync(d_ws, 0, 512, stream);

    GaussW gw;
    {
        double g[WIN], s = 0.0;
        for (int i = 0; i < WIN; ++i) {
            double d = (double)(i - 5);
            g[i] = exp(-(d * d) / (2.0 * 1.5 * 1.5));
            s += g[i];
        }
        for (int i = 0; i < WIN; ++i) gw.w[i] = (float)(g[i] / s);
    }

    dim3 grid(GRID_X, GRID_Y, GRID_Z);        // 8 x 16 x 96
    ssim_v10_kernel<<<grid, 256, 0, stream>>>(X, Y, gw, ws_u32, out);
}

// Round 6
// 287.537 us; speedup vs baseline: 1.0123x; 1.0123x over previous
//
#include <hip/hip_runtime.h>
#include <math.h>

// SSIM loss, (32,3,512,512) fp32, 11x11 sigma=1.5 separable Gaussian, VALID.
// R11 = R9 structure (two kernels, plain partial stores -- R10's fusion saved
// no harness overhead: bench-minus-exec gap is ~137-140 us regardless of node
// count, while the in-kernel coherence protocol cost +35 us; reverted) with a
// smaller tile for occupancy:
//  - TO_R 32->24: LDS 39424->29568 B -> 5 blocks/CU (20 waves, +25% hiding).
//    R9 was latency-bound: VALU-work 87 us-equiv vs dur 117.6, VALUBusy 74%,
//    LDS-capped at 4 blocks/CU.
//  - 4 waves x 6-row strips (16-row loops, 24 accumulators).
//  - tail round (40 halo cols) moved to WAVE 3: phase 2 uses only 192 threads
//    (24 rows x 8 col-groups), so wave 3 has no phase-2 work -- it absorbs
//    the extra round where it costs nothing.
// Inherited: 4 conv fields {x,y,(x+y)^2,(x-y)^2} (sig1+sig2=(P+M)/2-mu1^2-mu2^2,
// sig12=(P-M)/4-mu12); SGPR row base + clamp-free interior path; stride-77
// scalar b32 LDS (2-way max = free); relu folded into numerator; one rcp;
// separate reduce kernel (no fences, no contended atomics).

#define WIN   11
#define IMG   512
#define OUT_N 502
#define TO_R  24                 // output rows per block (4 waves x 6)
#define SR    6                  // output rows per strip
#define KR    (SR + WIN - 1)     // 16 input rows per strip
#define TO_C  64                 // output cols per block
#define TI_C  (TO_C + WIN - 1)   // 74 input cols
#define VB_W  77                 // ODD row stride -> conflict-free scalar reads
#define NF    4                  // conv fields: x, y, (x+y)^2, (x-y)^2
#define C1F   6.5025f
#define C2F   58.5225f
#define GRID_X 8
#define GRID_Y 21
#define GRID_Z 96
#define NBLOCKS (GRID_X * GRID_Y * GRID_Z)   // 16128

struct GaussW { float w[WIN]; };

// Vertical 11-tap over KR=16 input rows -> SR=6 output rows x 4 fields, 1 col.
// CR: clamp rows (only last row-block). CC: clamp column (tail round only).
template<bool CR, bool CC>
__device__ __forceinline__ void vert_task(
    const float* __restrict__ Xp, const float* __restrict__ Yp,
    const GaussW& gw, float (*vb)[TO_R][VB_W],
    int r0, int gc, int i0, int c)
{
    if (CC) gc = min(gc, IMG - 1);
    float a0[SR] = {0}, a1[SR] = {0}, a2[SR] = {0}, a3[SR] = {0};
#pragma unroll
    for (int k = 0; k < KR; ++k) {            // 6 outputs need 16 input rows
        int gr = r0 + k;
        if (CR) gr = min(gr, IMG - 1);
        size_t off = (size_t)gr * IMG + gc;   // uniform part scalarizes when
        float x = Xp[off];                    // r0 came from readfirstlane
        float y = Yp[off];
        float s = x + y, d = x - y;
        float ss = s * s, dd = d * d;
        const int jlo = (k > 10) ? (k - 10) : 0;
        const int jhi = (k < SR - 1) ? k : (SR - 1);
#pragma unroll
        for (int j = jlo; j <= jhi; ++j) {
            float wv = gw.w[k - j];
            a0[j] += wv * x;
            a1[j] += wv * y;
            a2[j] += wv * ss;
            a3[j] += wv * dd;
        }
    }
#pragma unroll
    for (int j = 0; j < SR; ++j) {            // stride-1 across lanes: free
        int i = i0 + j;
        vb[0][i][c] = a0[j];
        vb[1][i][c] = a1[j];
        vb[2][i][c] = a2[j];
        vb[3][i][c] = a3[j];
    }
}

__global__ __launch_bounds__(256) void ssim_v11_kernel(
    const float* __restrict__ X, const float* __restrict__ Y,
    GaussW gw, float* __restrict__ partial)
{
    // vertically filtered fields: [field][out_row][col], stride 77
    __shared__ float vb[NF][TO_R][VB_W];  // 29568 B -> 5 blocks/CU

    const int plane = blockIdx.z;
    const int ox0 = blockIdx.x * TO_C;    // 64-aligned global columns
    const int oy0 = blockIdx.y * TO_R;
    const float* Xp = X + (size_t)plane * IMG * IMG;
    const float* Yp = Y + (size_t)plane * IMG * IMG;
    const int tid  = threadIdx.x;
    const int wave = tid >> 6;
    const int lane = tid & 63;

    // ---- Phase 1: vertical 11-tap ----
    // Round 1: strip = wave (6 rows), col = lane. Rows wave-uniform -> SGPR.
    // gc = ox0 + lane <= 448 + 63 = 511: never needs the col clamp.
    {
        const int r0 = __builtin_amdgcn_readfirstlane(oy0 + wave * SR);
        const int gc = ox0 + lane;
        if (blockIdx.y == GRID_Y - 1)
            vert_task<true,  false>(Xp, Yp, gw, vb, r0, gc, wave * SR, lane);
        else
            vert_task<false, false>(Xp, Yp, gw, vb, r0, gc, wave * SR, lane);
    }
    // Round 2: WAVE 3 covers the 4 strips x 10 tail cols (c = 64..73) --
    // wave 3 has no phase-2 work (phase 2 uses 192 threads), so the extra
    // round lands on the otherwise-idle wave. Clamps are no-ops interior.
    if (wave == 3 && lane < 40) {
        const int s = lane / 10;              // strip 0..3 (compiler magic-mul)
        const int c = TO_C + (lane - s * 10); // 64..73
        vert_task<true, true>(Xp, Yp, gw, vb, oy0 + s * SR, ox0 + c, s * SR, c);
    }
    __syncthreads();

    // ---- Phase 2: horizontal 11-tap + SSIM, 8 outputs/thread ----
    // 192 threads (i = 0..23); wave 3 (tid >= 192) skips via execz.
    const int i  = tid >> 3;              // 0..31, valid < 24
    const int c0 = (tid & 7) * 8;         // 0..56
    const int gi = oy0 + i;
    float psum = 0.f;
    if (i < TO_R) {
        float m[NF][8];
#pragma unroll
        for (int f = 0; f < NF; ++f) {
            float v[18];
#pragma unroll
            for (int k = 0; k < 18; ++k) v[k] = vb[f][i][c0 + k];  // 2-way max
#pragma unroll
            for (int oc = 0; oc < 8; ++oc) {
                float s = 0.f;
#pragma unroll
                for (int k = 0; k < WIN; ++k) s += gw.w[k] * v[oc + k];
                m[f][oc] = s;
            }
        }
#pragma unroll
        for (int oc = 0; oc < 8; ++oc) {
            int gj = ox0 + c0 + oc;
            if (gi < OUT_N && gj < OUT_N) {
                float m1 = m[0][oc], m2 = m[1][oc];
                float P  = m[2][oc], M  = m[3][oc];
                float mu1s = m1 * m1, mu2s = m2 * m2, mu12 = m1 * m2;
                float sumvar = 0.5f  * (P + M) - mu1s - mu2s;   // sig1+sig2
                float sig12  = 0.25f * (P - M) - mu12;
                // ssim = [(2mu12+C1)/(mu1s+mu2s+C1)]*relu[(2sig12+C2)/(sumvar+C2)]
                // first factor and both denominators > 0 -> relu folds into num.
                float num = (2.f * mu12 + C1F) * (2.f * sig12 + C2F);
                float den = (mu1s + mu2s + C1F) * (sumvar + C2F);
                num = fmaxf(num, 0.f);
                psum += num * __builtin_amdgcn_rcpf(den);
            }
        }
    }

    // ---- block reduction -> one plain store per block (NO atomic) ----
#pragma unroll
    for (int off = 32; off > 0; off >>= 1)
        psum += __shfl_down(psum, off, 64);
    __shared__ float wsum[4];
    if ((tid & 63) == 0) wsum[tid >> 6] = psum;
    __syncthreads();
    if (tid == 0) {
        float s = wsum[0] + wsum[1] + wsum[2] + wsum[3];
        partial[((size_t)blockIdx.z * GRID_Y + blockIdx.y) * GRID_X + blockIdx.x] = s;
    }
}

__global__ __launch_bounds__(256) void ssim_reduce_kernel(
    const float* __restrict__ partial, float* __restrict__ out)
{
    const int tid = threadIdx.x;
    double s = 0.0;
    for (int i = tid; i < NBLOCKS; i += 256)      // 63 coalesced loads/thread
        s += (double)partial[i];
#pragma unroll
    for (int off = 32; off > 0; off >>= 1)
        s += __shfl_down(s, off, 64);
    __shared__ double wsum[4];
    if ((tid & 63) == 0) wsum[tid >> 6] = s;
    __syncthreads();
    if (tid == 0) {
        double a = wsum[0] + wsum[1] + wsum[2] + wsum[3];
        const double count = (double)GRID_Z * OUT_N * OUT_N;
        out[0] = (float)(1.0 - a / count);
    }
}

extern "C" void kernel_launch(void* const* d_in, const int* in_sizes, int n_in,
                              void* d_out, int out_size, void* d_ws, size_t ws_size,
                              hipStream_t stream) {
    (void)in_sizes; (void)n_in; (void)out_size; (void)ws_size;
    const float* X = (const float*)d_in[0];
    const float* Y = (const float*)d_in[1];
    float* out = (float*)d_out;
    float* partial = (float*)d_ws;        // 16128 floats = 63 KiB

    GaussW gw;
    {
        double g[WIN], s = 0.0;
        for (int i = 0; i < WIN; ++i) {
            double d = (double)(i - 5);
            g[i] = exp(-(d * d) / (2.0 * 1.5 * 1.5));
            s += g[i];
        }
        for (int i = 0; i < WIN; ++i) gw.w[i] = (float)(g[i] / s);
    }

    dim3 grid(GRID_X, GRID_Y, GRID_Z);        // 8 x 21 x 96
    ssim_v11_kernel<<<grid, 256, 0, stream>>>(X, Y, gw, partial);
    ssim_reduce_kernel<<<1, 256, 0, stream>>>(partial, out);
}

// Round 7
// 263.400 us; speedup vs baseline: 1.1050x; 1.0916x over previous
//
#include <hip/hip_runtime.h>
#include <math.h>

// SSIM loss, (32,3,512,512) fp32, 11x11 sigma=1.5 separable Gaussian, VALID.
// R12 = R9 geometry (R11's smaller tile reverted: occupancy is dynamically
// limited ~3 blocks/CU, not LDS-capped -- shrinking tiles just added halo
// overhead, 117.6->137.4) with the FMA streams PACKED into v_pk_fma_f32:
//  - fields are processed as f32x2 pairs: {x,y} and {(x+y)^2,(x-y)^2}.
//    Phase-1 j-loop: 2 pk_fma per tap instead of 4 fmac (352->176 issue
//    slots/task). Phase-2 horizontal conv: same pairing (352->176/thread).
//    Emitted via plain ext_vector_type(2) arithmetic (fmuladd.v2f32 ->
//    v_pk_fma_f32 on CDNA; if it ever splits, we're merely neutral).
//  - LDS element type is f32x2 (field pairs adjacent) -> ds_read_b64 /
//    ds_write_b64: DS instruction count halves. Pair-row stride 75: starts
//    cover 16 distinct even banks x 4 lanes = the wave64 b64 floor (512B /
//    128B-per-clk = 4 clk) -- conflict-free in timing terms, though the
//    SQ_LDS_BANK_CONFLICT counter may read higher (benign, pre-declared).
//  - VGPR cost of pairing is free: LDS caps at 4 blocks/CU = 4 waves/SIMD,
//    allowed up to VGPR=128.
// Inherited from R9: 4 conv fields via s=x+y,d=x-y identity; phase-1 round 1
// = 4 full waves w/ SGPR row base + clamp-free interior; wave-0 tail round;
// relu folded into SSIM numerator; one rcp; block partial -> plain store;
// separate reduce kernel (no fences, no contended atomics, no memset).

#define WIN   11
#define IMG   512
#define OUT_N 502
#define TO_R  32                 // output rows per block (4 waves x 8)
#define TO_C  64                 // output cols per block
#define TI_C  (TO_C + WIN - 1)   // 74 input cols
#define VB_W  75                 // pair-row stride (f32x2 units), odd
#define C1F   6.5025f
#define C2F   58.5225f
#define GRID_X 8
#define GRID_Y 16
#define GRID_Z 96
#define NBLOCKS (GRID_X * GRID_Y * GRID_Z)   // 12288

typedef float f32x2 __attribute__((ext_vector_type(2)));

struct GaussW2 { f32x2 w[WIN]; };   // both halves = w[k] (broadcast pairs)

// Vertical 11-tap over 18 input rows -> 8 output rows x 2 field-pairs, 1 col.
// CR: clamp rows (only last row-block). CC: clamp column (tail round only).
template<bool CR, bool CC>
__device__ __forceinline__ void vert_task(
    const float* __restrict__ Xp, const float* __restrict__ Yp,
    const GaussW2& gw, f32x2 (*vb)[TO_R][VB_W],
    int r0, int gc, int i0, int c)
{
    if (CC) gc = min(gc, IMG - 1);
    f32x2 a01[8] = {}, a23[8] = {};
#pragma unroll
    for (int k = 0; k < 18; ++k) {            // 8 outputs need 18 input rows
        int gr = r0 + k;
        if (CR) gr = min(gr, IMG - 1);
        size_t off = (size_t)gr * IMG + gc;   // uniform part scalarizes when
        float x = Xp[off];                    // r0 came from readfirstlane
        float y = Yp[off];
        f32x2 xy = {x, y};
        f32x2 sd = {x + y, x - y};
        sd = sd * sd;                         // v_pk_mul_f32: {(x+y)^2,(x-y)^2}
        const int jlo = (k > 10) ? (k - 10) : 0;
        const int jhi = (k < 7) ? k : 7;
#pragma unroll
        for (int j = jlo; j <= jhi; ++j) {
            f32x2 wv = gw.w[k - j];
            a01[j] += wv * xy;                // v_pk_fma_f32
            a23[j] += wv * sd;                // v_pk_fma_f32
        }
    }
#pragma unroll
    for (int j = 0; j < 8; ++j) {             // ds_write_b64, b64 floor
        int i = i0 + j;
        vb[0][i][c] = a01[j];
        vb[1][i][c] = a23[j];
    }
}

__global__ __launch_bounds__(256) void ssim_v12_kernel(
    const float* __restrict__ X, const float* __restrict__ Y,
    GaussW2 gw, float* __restrict__ partial)
{
    // vertically filtered field-pairs: [pair][out_row][col], pair stride 75
    __shared__ f32x2 vb[2][TO_R][VB_W];   // 38400 B -> 4 blocks/CU

    const int plane = blockIdx.z;
    const int ox0 = blockIdx.x * TO_C;    // 64-aligned global columns
    const int oy0 = blockIdx.y * TO_R;
    const float* Xp = X + (size_t)plane * IMG * IMG;
    const float* Yp = Y + (size_t)plane * IMG * IMG;
    const int tid  = threadIdx.x;
    const int wave = tid >> 6;
    const int lane = tid & 63;

    // ---- Phase 1: vertical 11-tap ----
    // Round 1: strip = wave, col = lane. Rows wave-uniform -> SGPR base.
    // gc = ox0 + lane <= 448 + 63 = 511: never needs the col clamp.
    {
        const int r0 = __builtin_amdgcn_readfirstlane(oy0 + wave * 8);
        const int gc = ox0 + lane;
        if (blockIdx.y == GRID_Y - 1)
            vert_task<true,  false>(Xp, Yp, gw, vb, r0, gc, wave * 8, lane);
        else
            vert_task<false, false>(Xp, Yp, gw, vb, r0, gc, wave * 8, lane);
    }
    // Round 2: wave 0 covers the 4 strips x 10 tail cols (c = 64..73).
    // Always fully clamped (40 lanes; clamps are no-ops on interior blocks).
    if (wave == 0 && lane < 40) {
        const int s = lane / 10;              // compiler magic-muls
        const int c = TO_C + (lane - s * 10); // 64..73
        vert_task<true, true>(Xp, Yp, gw, vb, oy0 + s * 8, ox0 + c, s * 8, c);
    }
    __syncthreads();

    // ---- Phase 2: horizontal 11-tap + SSIM, 8 outputs/thread ----
    const int i  = tid >> 3;              // 0..31
    const int c0 = (tid & 7) * 8;         // 0..56
    const int gi = oy0 + i;
    f32x2 m01[8] = {}, m23[8] = {};
    {
        f32x2 v[18];
#pragma unroll
        for (int k = 0; k < 18; ++k) v[k] = vb[0][i][c0 + k];  // ds_read_b64
#pragma unroll
        for (int oc = 0; oc < 8; ++oc)
#pragma unroll
            for (int k = 0; k < WIN; ++k)
                m01[oc] += gw.w[k] * v[oc + k];                // v_pk_fma_f32
    }
    {
        f32x2 v[18];
#pragma unroll
        for (int k = 0; k < 18; ++k) v[k] = vb[1][i][c0 + k];  // ds_read_b64
#pragma unroll
        for (int oc = 0; oc < 8; ++oc)
#pragma unroll
            for (int k = 0; k < WIN; ++k)
                m23[oc] += gw.w[k] * v[oc + k];                // v_pk_fma_f32
    }

    float psum = 0.f;
#pragma unroll
    for (int oc = 0; oc < 8; ++oc) {
        int gj = ox0 + c0 + oc;
        if (gi < OUT_N && gj < OUT_N) {
            float m1 = m01[oc].x, m2 = m01[oc].y;
            float P  = m23[oc].x, M  = m23[oc].y;
            float mu1s = m1 * m1, mu2s = m2 * m2, mu12 = m1 * m2;
            float sumvar = 0.5f  * (P + M) - mu1s - mu2s;   // sig1+sig2
            float sig12  = 0.25f * (P - M) - mu12;
            // ssim = [(2mu12+C1)/(mu1s+mu2s+C1)] * relu[(2sig12+C2)/(sumvar+C2)]
            // first factor and both denominators are > 0 -> relu folds into num.
            float num = (2.f * mu12 + C1F) * (2.f * sig12 + C2F);
            float den = (mu1s + mu2s + C1F) * (sumvar + C2F);
            num = fmaxf(num, 0.f);
            psum += num * __builtin_amdgcn_rcpf(den);
        }
    }

    // ---- block reduction -> one plain store per block (NO atomic) ----
#pragma unroll
    for (int off = 32; off > 0; off >>= 1)
        psum += __shfl_down(psum, off, 64);
    __shared__ float wsum[4];
    if ((tid & 63) == 0) wsum[tid >> 6] = psum;
    __syncthreads();
    if (tid == 0) {
        float s = wsum[0] + wsum[1] + wsum[2] + wsum[3];
        partial[((size_t)blockIdx.z * GRID_Y + blockIdx.y) * GRID_X + blockIdx.x] = s;
    }
}

__global__ __launch_bounds__(256) void ssim_reduce_kernel(
    const float* __restrict__ partial, float* __restrict__ out)
{
    const int tid = threadIdx.x;
    double s = 0.0;
    for (int i = tid; i < NBLOCKS; i += 256)      // 48 coalesced loads/thread
        s += (double)partial[i];
#pragma unroll
    for (int off = 32; off > 0; off >>= 1)
        s += __shfl_down(s, off, 64);
    __shared__ double wsum[4];
    if ((tid & 63) == 0) wsum[tid >> 6] = s;
    __syncthreads();
    if (tid == 0) {
        double a = wsum[0] + wsum[1] + wsum[2] + wsum[3];
        const double count = (double)GRID_Z * OUT_N * OUT_N;
        out[0] = (float)(1.0 - a / count);
    }
}

extern "C" void kernel_launch(void* const* d_in, const int* in_sizes, int n_in,
                              void* d_out, int out_size, void* d_ws, size_t ws_size,
                              hipStream_t stream) {
    (void)in_sizes; (void)n_in; (void)out_size; (void)ws_size;
    const float* X = (const float*)d_in[0];
    const float* Y = (const float*)d_in[1];
    float* out = (float*)d_out;
    float* partial = (float*)d_ws;        // 12288 floats = 48 KiB

    GaussW2 gw;
    {
        double g[WIN], s = 0.0;
        for (int i = 0; i < WIN; ++i) {
            double d = (double)(i - 5);
            g[i] = exp(-(d * d) / (2.0 * 1.5 * 1.5));
            s += g[i];
        }
        for (int i = 0; i < WIN; ++i) {
            float w = (float)(g[i] / s);
            gw.w[i].x = w;
            gw.w[i].y = w;
        }
    }

    dim3 grid(GRID_X, GRID_Y, GRID_Z);        // 8 x 16 x 96
    ssim_v12_kernel<<<grid, 256, 0, stream>>>(X, Y, gw, partial);
    ssim_reduce_kernel<<<1, 256, 0, stream>>>(partial, out);
}